// Round 2
// baseline (1337.977 us; speedup 1.0000x reference)
//
#include <hip/hip_runtime.h>
#include <math.h>

#define T_DIM 16384
#define A_DIM 128
#define K_DIM 128
#define N_STEPS 16
#define E_DIM 126
#define NSEQ 4

// fm tiling: 32 atoms x 256 t per block -> 4 atiles x 64 ttiles = 256 blocks/seq
#define AT 32
#define TT 256
#define NB_PER_SEQ 256

// pack (value, flat_idx) into u64 so atomicMax picks (max value, min idx on tie)
__device__ inline unsigned long long pack_vi(float v, int fi) {
    unsigned int b = __float_as_uint(v);
    b = (b & 0x80000000u) ? ~b : (b | 0x80000000u);
    return ((unsigned long long)b << 32) | (unsigned int)(~fi);
}
__device__ inline void unpack_vi(unsigned long long p, float* v, int* fi) {
    unsigned int lo = (unsigned int)(p & 0xffffffffu);
    unsigned int b = (unsigned int)(p >> 32);
    unsigned int fb = (b & 0x80000000u) ? (b & 0x7fffffffu) : ~b;
    *v = __uint_as_float(fb);
    *fi = (int)(~lo);
}

// ---------------------------------------------------------------------------
__global__ void k_dunit(const float* __restrict__ d, float* __restrict__ du) {
    int a = blockIdx.x;
    int k = threadIdx.x;
    float v = d[a * K_DIM + k];
    __shared__ float s[K_DIM];
    s[k] = v * v;
    __syncthreads();
    for (int off = K_DIM / 2; off > 0; off >>= 1) {
        if (k < off) s[k] += s[k + off];
        __syncthreads();
    }
    float norm = sqrtf(s[0]) + 1e-8f;
    du[a * K_DIM + k] = v / norm;
}

// res init + control-state init (cnt/slot/dirty) — everything ws-resident must
// be re-initialized every call (harness poisons ws with 0xAA).
__global__ void k_init(const float* __restrict__ a, const float* __restrict__ b,
                       float* __restrict__ res, unsigned long long* __restrict__ slot,
                       int* __restrict__ cnt, int* __restrict__ dirty) {
    int i = blockIdx.x * blockDim.x + threadIdx.x;
    if (i < 2 * T_DIM) res[i] = a[i];
    else if (i < 4 * T_DIM) res[i] = b[i - 2 * T_DIM];
    if (blockIdx.x == 0) {
        int tid = threadIdx.x;
        if (tid < N_STEPS * NSEQ) { cnt[tid] = 0; slot[tid] = 0ULL; }
        if (tid < 2 * NSEQ) dirty[tid] = (tid & 1) ? T_DIM : 0;  // step0: all dirty
    }
}

// ---------------------------------------------------------------------------
// One launch per step. Dirty blocks recompute their fm tile (bit-identical
// k-ascending FMA) and refresh their persistent packed max; clean blocks just
// contribute their stored max. Last-arriving block per seq does the finalize.
__global__ __launch_bounds__(256) void k_step(
    float* __restrict__ res, const float* __restrict__ du,
    const float* __restrict__ ae, float* __restrict__ emb,
    unsigned long long* __restrict__ pmax, unsigned long long* __restrict__ slot,
    int* __restrict__ cnt, int* __restrict__ dirty, int step) {

    int seq = blockIdx.y;
    int blk = blockIdx.x;                 // [0, 256)
    int atile = blk >> 6;                 // 0..3
    int ttile = blk & 63;                 // 0..63
    int a_base = atile * AT;
    int t0 = ttile * TT;
    int tid = threadIdx.x;

    int lo = dirty[step * 2 * NSEQ + seq * 2 + 0];
    int hi = dirty[step * 2 * NSEQ + seq * 2 + 1];
    bool dirty_blk = (t0 < hi) && (t0 + TT > lo);

    __shared__ float du_sh[AT * K_DIM];      // 16 KB
    __shared__ float res_sh[TT + K_DIM];     // 1.5 KB
    __shared__ float rv_sh[256];
    __shared__ int   ri_sh[256];
    __shared__ int   last_flag;

    int sslot = step * NSEQ + seq;

    if (dirty_blk) {
        const float* resS = res + seq * T_DIM;
        for (int i = tid; i < AT * K_DIM; i += 256) du_sh[i] = du[a_base * K_DIM + i];
        for (int i = tid; i < TT + K_DIM - 1; i += 256) {
            int t = t0 + i - K_DIM / 2;
            res_sh[i] = (t >= 0 && t < T_DIM) ? resS[t] : 0.0f;
        }
        __syncthreads();

        int tg = tid & 63;       // t lane (stride-1 LDS)
        int ag = tid >> 6;       // wave-uniform atom group -> du reads broadcast
        int a0 = ag * 8;

        float acc[8][4];
        #pragma unroll
        for (int i = 0; i < 8; i++)
            #pragma unroll
            for (int j = 0; j < 4; j++) acc[i][j] = 0.0f;

        for (int k = 0; k < K_DIM; k += 2) {
            float2 dv[8];
            #pragma unroll
            for (int i = 0; i < 8; i++)
                dv[i] = *(const float2*)&du_sh[(a0 + i) * K_DIM + k];  // 8B aligned (k even)
            #pragma unroll
            for (int j = 0; j < 4; j++) {
                float r0 = res_sh[tg + 64 * j + k];
                float r1 = res_sh[tg + 64 * j + k + 1];
                #pragma unroll
                for (int i = 0; i < 8; i++) {
                    acc[i][j] = fmaf(dv[i].x, r0, acc[i][j]);   // k
                    acc[i][j] = fmaf(dv[i].y, r1, acc[i][j]);   // k+1 (same order as ref)
                }
            }
        }

        float bv = -INFINITY;
        int bi = 0x7fffffff;
        #pragma unroll
        for (int i = 0; i < 8; i++) {
            int a = a_base + a0 + i;
            #pragma unroll
            for (int j = 0; j < 4; j++) {
                int t = t0 + tg + 64 * j;
                int fi = a * T_DIM + t;
                float v = acc[i][j];
                if (v > bv || (v == bv && fi < bi)) { bv = v; bi = fi; }
            }
        }
        rv_sh[tid] = bv;
        ri_sh[tid] = bi;
        __syncthreads();
        for (int off = 128; off > 0; off >>= 1) {
            if (tid < off) {
                float v2 = rv_sh[tid + off]; int i2 = ri_sh[tid + off];
                if (v2 > rv_sh[tid] || (v2 == rv_sh[tid] && i2 < ri_sh[tid])) {
                    rv_sh[tid] = v2; ri_sh[tid] = i2;
                }
            }
            __syncthreads();
        }
        if (tid == 0) {
            unsigned long long p = pack_vi(rv_sh[0], ri_sh[0]);
            pmax[seq * NB_PER_SEQ + blk] = p;      // persist for future clean steps
            atomicMax(&slot[sslot], p);
        }
    } else {
        if (tid == 0) atomicMax(&slot[sslot], pmax[seq * NB_PER_SEQ + blk]);
    }

    __threadfence();
    if (tid == 0) last_flag = (atomicAdd(&cnt[sslot], 1) == NB_PER_SEQ - 1);
    __syncthreads();
    if (!last_flag) return;

    // ---- finalize (exactly one block per seq reaches here) ----
    __threadfence();
    unsigned long long p = atomicAdd(&slot[sslot], 0ULL);
    float value; int fi;
    unpack_vi(p, &value, &fi);
    int ai = fi >> 14;
    int ti = fi & (T_DIM - 1);
    int pos_idx = value > 0.0f ? ti : 0;   // soft_dirac of all-zeros-row -> idx 0
    int atom_idx = value > 0.0f ? ai : 0;

    float* e = emb + (seq * N_STEPS + step) * 128;
    if (tid == 0) {
        e[0] = ((float)pos_idx / (float)(T_DIM - 1)) * 20.0f;
        e[1] = value;
    }
    if (tid == 1 && step + 1 < N_STEPS) {
        int nlo = ti - (K_DIM - 1); if (nlo < 0) nlo = 0;
        int nhi = ti + K_DIM;       if (nhi > T_DIM) nhi = T_DIM;
        dirty[(step + 1) * 2 * NSEQ + seq * 2 + 0] = nlo;
        dirty[(step + 1) * 2 * NSEQ + seq * 2 + 1] = nhi;
    }
    if (tid >= 2 && tid < 2 + E_DIM) e[tid] = ae[atom_idx * E_DIM + tid - 2];
    if (tid >= 128) {
        int k = tid - 128;
        int t = ti + k - K_DIM / 2;
        if (t >= 0 && t < T_DIM) res[seq * T_DIM + t] -= value * du[ai * K_DIM + k];
    }
}

// ---------------------------------------------------------------------------
// norms + canonical ordering + loss, single block
__global__ void k_tail(const float* __restrict__ res, const float* __restrict__ emb,
                       const float* __restrict__ proj, float* __restrict__ out) {
    int tid = threadIdx.x;  // 256
    __shared__ float sh[256];
    __shared__ float norms[NSEQ];
    for (int seq = 0; seq < NSEQ; seq++) {
        float s = 0.0f;
        for (int i = tid; i < T_DIM; i += 256) {
            float v = res[seq * T_DIM + i];
            s = fmaf(v, v, s);
        }
        sh[tid] = s;
        __syncthreads();
        for (int off = 128; off > 0; off >>= 1) {
            if (tid < off) sh[tid] += sh[tid + off];
            __syncthreads();
        }
        if (tid == 0) norms[seq] = sqrtf(sh[0]);
        __syncthreads();
    }

    __shared__ float keys[NSEQ][N_STEPS];
    __shared__ int   order[NSEQ][N_STEPS];
    if (tid < NSEQ * N_STEPS) {
        int seq = tid / N_STEPS, s = tid % N_STEPS;
        const float* e = emb + (seq * N_STEPS + s) * 128;
        float k = 0.0f;
        for (int d = 0; d < 128; d++) k = fmaf(e[d], proj[d], k);
        keys[seq][s] = k;
    }
    __syncthreads();
    if (tid < NSEQ) {
        int ord[N_STEPS];
        for (int i = 0; i < N_STEPS; i++) ord[i] = i;
        for (int i = 1; i < N_STEPS; i++) {      // stable ascending sort
            int oi = ord[i];
            float kv = keys[tid][oi];
            int j = i - 1;
            while (j >= 0 && keys[tid][ord[j]] > kv) { ord[j + 1] = ord[j]; j--; }
            ord[j + 1] = oi;
        }
        for (int i = 0; i < N_STEPS; i++) order[tid][i] = ord[i];
    }
    __syncthreads();
    float s = 0.0f;
    for (int idx = tid; idx < 2 * N_STEPS * 128; idx += 256) {
        int b = idx / (N_STEPS * 128);
        int st = (idx / 128) % N_STEPS;
        int d = idx % 128;
        float va = emb[((b    ) * N_STEPS + order[b    ][st]) * 128 + d];
        float vb = emb[((2 + b) * N_STEPS + order[2 + b][st]) * 128 + d];
        float df = va - vb;
        s = fmaf(df, df, s);
    }
    sh[tid] = s;
    __syncthreads();
    for (int off = 128; off > 0; off >>= 1) {
        if (tid < off) sh[tid] += sh[tid + off];
        __syncthreads();
    }
    if (tid == 0) {
        float mse = sh[0] / (float)(2 * N_STEPS * 128);
        float mad = 0.5f * (fabsf(norms[0] - norms[2]) + fabsf(norms[1] - norms[3]));
        out[0] = mse + mad;
    }
}

// ---------------------------------------------------------------------------
extern "C" void kernel_launch(void* const* d_in, const int* in_sizes, int n_in,
                              void* d_out, int out_size, void* d_ws, size_t ws_size,
                              hipStream_t stream) {
    const float* a    = (const float*)d_in[0];
    const float* b    = (const float*)d_in[1];
    const float* d    = (const float*)d_in[2];
    const float* ae   = (const float*)d_in[3];
    const float* proj = (const float*)d_in[4];
    float* out = (float*)d_out;

    float* ws  = (float*)d_ws;
    float* res = ws;                              // 65536
    float* du  = res + NSEQ * T_DIM;              // 16384
    float* emb = du + A_DIM * K_DIM;              // 8192
    unsigned long long* pmax = (unsigned long long*)(emb + NSEQ * N_STEPS * 128); // 1024 (8B-aligned: 90112*4 bytes)
    unsigned long long* slot = pmax + NSEQ * NB_PER_SEQ;   // 64
    int* cnt   = (int*)(slot + N_STEPS * NSEQ);            // 64
    int* dirty = cnt + N_STEPS * NSEQ;                     // 17*8

    k_dunit<<<A_DIM, K_DIM, 0, stream>>>(d, du);
    k_init<<<NSEQ * T_DIM / 256, 256, 0, stream>>>(a, b, res, slot, cnt, dirty);

    dim3 grid(NB_PER_SEQ, NSEQ);
    for (int step = 0; step < N_STEPS; step++) {
        k_step<<<grid, 256, 0, stream>>>(res, du, ae, emb, pmax, slot, cnt, dirty, step);
    }

    k_tail<<<1, 256, 0, stream>>>(res, emb, proj, out);
}

// Round 3
// 379.254 us; speedup vs baseline: 3.5279x; 3.5279x over previous
//
#include <hip/hip_runtime.h>
#include <math.h>

#define T_DIM 16384
#define A_DIM 128
#define K_DIM 128
#define N_STEPS 16
#define E_DIM 126
#define NSEQ 4

// fm tiling: 32 atoms x 256 t per block -> 4 atiles x 64 ttiles = 256 tiles/seq
#define AT 32
#define TT 256
#define NTT 64
#define NB_PER_SEQ 256

// order-preserving pack: bigger u64 == (bigger value, then smaller flat idx)
__device__ inline unsigned long long pack_vi(float v, int fi) {
    unsigned int b = __float_as_uint(v);
    b = (b & 0x80000000u) ? ~b : (b | 0x80000000u);
    return ((unsigned long long)b << 32) | (unsigned int)(~fi);
}
__device__ inline void unpack_vi(unsigned long long p, float* v, int* fi) {
    unsigned int lo = (unsigned int)(p & 0xffffffffu);
    unsigned int b = (unsigned int)(p >> 32);
    unsigned int fb = (b & 0x80000000u) ? (b & 0x7fffffffu) : ~b;
    *v = __uint_as_float(fb);
    *fi = (int)(~lo);
}

// ---------------------------------------------------------------------------
__global__ void k_dunit(const float* __restrict__ d, float* __restrict__ du) {
    int a = blockIdx.x;
    int k = threadIdx.x;
    float v = d[a * K_DIM + k];
    __shared__ float s[K_DIM];
    s[k] = v * v;
    __syncthreads();
    for (int off = K_DIM / 2; off > 0; off >>= 1) {
        if (k < off) s[k] += s[k + off];
        __syncthreads();
    }
    float norm = sqrtf(s[0]) + 1e-8f;
    du[a * K_DIM + k] = v / norm;
}

__global__ void k_init(const float* __restrict__ a, const float* __restrict__ b,
                       float* __restrict__ res, int* __restrict__ cnt,
                       int* __restrict__ dirty) {
    int i = blockIdx.x * blockDim.x + threadIdx.x;
    if (i < 2 * T_DIM) res[i] = a[i];
    else if (i < 4 * T_DIM) res[i] = b[i - 2 * T_DIM];
    if (blockIdx.x == 0) {
        int tid = threadIdx.x;
        if (tid < N_STEPS * NSEQ) cnt[tid] = 0;
        if (tid < 2 * NSEQ) dirty[tid] = (tid & 1) ? T_DIM : 0;
    }
}

// ---------------------------------------------------------------------------
// compute one (a_base, t0) tile; returns packed block max (same value in all
// threads after the internal sync). FMA order identical to R2 (absmax 0.0).
__device__ inline unsigned long long compute_tile(
    const float* __restrict__ res, const float* __restrict__ du,
    int seq, int a_base, int t0, int tid,
    float* du_sh, float* res_sh, float* rv_sh, int* ri_sh) {

    const float* resS = res + seq * T_DIM;
    for (int i = tid; i < AT * K_DIM; i += 256) du_sh[i] = du[a_base * K_DIM + i];
    for (int i = tid; i < TT + K_DIM - 1; i += 256) {
        int t = t0 + i - K_DIM / 2;
        res_sh[i] = (t >= 0 && t < T_DIM) ? resS[t] : 0.0f;
    }
    __syncthreads();

    int tg = tid & 63;
    int ag = tid >> 6;
    int a0 = ag * 8;

    float acc[8][4];
    #pragma unroll
    for (int i = 0; i < 8; i++)
        #pragma unroll
        for (int j = 0; j < 4; j++) acc[i][j] = 0.0f;

    for (int k = 0; k < K_DIM; k += 2) {
        float2 dv[8];
        #pragma unroll
        for (int i = 0; i < 8; i++)
            dv[i] = *(const float2*)&du_sh[(a0 + i) * K_DIM + k];
        #pragma unroll
        for (int j = 0; j < 4; j++) {
            float r0 = res_sh[tg + 64 * j + k];
            float r1 = res_sh[tg + 64 * j + k + 1];
            #pragma unroll
            for (int i = 0; i < 8; i++) {
                acc[i][j] = fmaf(dv[i].x, r0, acc[i][j]);
                acc[i][j] = fmaf(dv[i].y, r1, acc[i][j]);
            }
        }
    }

    float bv = -INFINITY;
    int bi = 0x7fffffff;
    #pragma unroll
    for (int i = 0; i < 8; i++) {
        int a = a_base + a0 + i;
        #pragma unroll
        for (int j = 0; j < 4; j++) {
            int t = t0 + tg + 64 * j;
            int fi = a * T_DIM + t;
            float v = acc[i][j];
            if (v > bv || (v == bv && fi < bi)) { bv = v; bi = fi; }
        }
    }
    rv_sh[tid] = bv;
    ri_sh[tid] = bi;
    __syncthreads();
    for (int off = 128; off > 0; off >>= 1) {
        if (tid < off) {
            float v2 = rv_sh[tid + off]; int i2 = ri_sh[tid + off];
            if (v2 > rv_sh[tid] || (v2 == rv_sh[tid] && i2 < ri_sh[tid])) {
                rv_sh[tid] = v2; ri_sh[tid] = i2;
            }
        }
        __syncthreads();
    }
    return pack_vi(rv_sh[0], ri_sh[0]);
}

__device__ inline void finalize_step(
    unsigned long long p, int step, int seq, int tid,
    const float* __restrict__ du, const float* __restrict__ ae,
    float* __restrict__ emb, float* __restrict__ res, int* __restrict__ dirty) {
    float value; int fi;
    unpack_vi(p, &value, &fi);
    int ai = fi >> 14;
    int ti = fi & (T_DIM - 1);
    int pos_idx = value > 0.0f ? ti : 0;
    int atom_idx = value > 0.0f ? ai : 0;

    float* e = emb + (seq * N_STEPS + step) * 128;
    if (tid == 0) {
        e[0] = ((float)pos_idx / (float)(T_DIM - 1)) * 20.0f;
        e[1] = value;
    }
    if (tid == 1 && step + 1 < N_STEPS) {
        int nlo = ti - (K_DIM - 1); if (nlo < 0) nlo = 0;
        int nhi = ti + K_DIM;       if (nhi > T_DIM) nhi = T_DIM;
        dirty[(step + 1) * 2 * NSEQ + seq * 2 + 0] = nlo;
        dirty[(step + 1) * 2 * NSEQ + seq * 2 + 1] = nhi;
    }
    if (tid >= 2 && tid < 2 + E_DIM) e[tid] = ae[atom_idx * E_DIM + tid - 2];
    if (tid >= 128) {
        int k = tid - 128;
        int t = ti + k - K_DIM / 2;
        if (t >= 0 && t < T_DIM) res[seq * T_DIM + t] -= value * du[ai * K_DIM + k];
    }
}

// ---------------------------------------------------------------------------
// step 0: full fm, 256 blocks/seq; last block per seq reduces pmax + finalizes
__global__ __launch_bounds__(256) void k_step_full(
    float* __restrict__ res, const float* __restrict__ du,
    const float* __restrict__ ae, float* __restrict__ emb,
    unsigned long long* __restrict__ pmax, int* __restrict__ cnt,
    int* __restrict__ dirty) {

    int seq = blockIdx.y;
    int blk = blockIdx.x;
    int a_base = (blk >> 6) * AT;
    int t0 = (blk & 63) * TT;
    int tid = threadIdx.x;

    __shared__ float du_sh[AT * K_DIM];
    __shared__ float res_sh[TT + K_DIM];
    __shared__ float rv_sh[256];
    __shared__ int   ri_sh[256];
    __shared__ unsigned long long pm_sh[256];
    __shared__ int last_flag;

    unsigned long long p = compute_tile(res, du, seq, a_base, t0, tid,
                                        du_sh, res_sh, rv_sh, ri_sh);
    if (tid == 0) {
        pmax[seq * NB_PER_SEQ + blk] = p;
        __threadfence();
        last_flag = (atomicAdd(&cnt[seq], 1) == NB_PER_SEQ - 1);
    }
    __syncthreads();
    if (!last_flag) return;

    __threadfence();  // acquire: other blocks' pmax writes
    pm_sh[tid] = pmax[seq * NB_PER_SEQ + tid];
    __syncthreads();
    for (int off = 128; off > 0; off >>= 1) {
        if (tid < off) { if (pm_sh[tid + off] > pm_sh[tid]) pm_sh[tid] = pm_sh[tid + off]; }
        __syncthreads();
    }
    finalize_step(pm_sh[0], 0, seq, tid, du, ae, emb, res, dirty);
}

// steps 1..15: 8 blocks/seq recompute dirty tiles; last arrival reduces+finalizes
__global__ __launch_bounds__(256) void k_step_inc(
    float* __restrict__ res, const float* __restrict__ du,
    const float* __restrict__ ae, float* __restrict__ emb,
    unsigned long long* __restrict__ pmax, int* __restrict__ cnt,
    int* __restrict__ dirty, int step) {

    int seq = blockIdx.y;
    int blk = blockIdx.x;                // 0..7
    int tid = threadIdx.x;

    __shared__ float du_sh[AT * K_DIM];
    __shared__ float res_sh[TT + K_DIM];
    __shared__ float rv_sh[256];
    __shared__ int   ri_sh[256];
    __shared__ unsigned long long pm_sh[256];
    __shared__ int last_flag;

    int lo = dirty[step * 2 * NSEQ + seq * 2 + 0];
    int hi = dirty[step * 2 * NSEQ + seq * 2 + 1];
    int atile = blk >> 1;
    int ttile = (lo >> 8) + (blk & 1);   // dirty window (<=255 wide) spans <=2 ttiles
    bool valid = (ttile < NTT) && (ttile * TT < hi);

    if (valid) {
        unsigned long long p = compute_tile(res, du, seq, atile * AT, ttile * TT,
                                            tid, du_sh, res_sh, rv_sh, ri_sh);
        if (tid == 0) pmax[seq * NB_PER_SEQ + atile * NTT + ttile] = p;
    }
    if (tid == 0) {
        __threadfence();
        last_flag = (atomicAdd(&cnt[step * NSEQ + seq], 1) == 7);
    }
    __syncthreads();
    if (!last_flag) return;

    __threadfence();
    pm_sh[tid] = pmax[seq * NB_PER_SEQ + tid];
    __syncthreads();
    for (int off = 128; off > 0; off >>= 1) {
        if (tid < off) { if (pm_sh[tid + off] > pm_sh[tid]) pm_sh[tid] = pm_sh[tid + off]; }
        __syncthreads();
    }
    finalize_step(pm_sh[0], step, seq, tid, du, ae, emb, res, dirty);
}

// ---------------------------------------------------------------------------
// norms + ordering + loss; 1 block x 1024 threads, vectorized & parallel
__global__ __launch_bounds__(1024) void k_tail(
    const float* __restrict__ res, const float* __restrict__ emb,
    const float* __restrict__ proj, float* __restrict__ out) {
    int tid = threadIdx.x;
    __shared__ float sh[1024];
    __shared__ float norms[NSEQ];
    __shared__ float keys[NSEQ][N_STEPS];
    __shared__ int   order[NSEQ][N_STEPS];

    // --- norms: 256 threads per seq, float4 x16 each ---
    {
        int seq = tid >> 8;
        int ln  = tid & 255;
        const float4* r4 = (const float4*)(res + seq * T_DIM);
        float s = 0.0f;
        #pragma unroll
        for (int j = 0; j < 16; j++) {
            float4 v = r4[j * 256 + ln];
            s = fmaf(v.x, v.x, s); s = fmaf(v.y, v.y, s);
            s = fmaf(v.z, v.z, s); s = fmaf(v.w, v.w, s);
        }
        sh[tid] = s;
        __syncthreads();
        for (int off = 128; off > 0; off >>= 1) {
            if (ln < off) sh[tid] += sh[tid + off];
            __syncthreads();
        }
        if (ln == 0) norms[seq] = sqrtf(sh[tid]);
        __syncthreads();
    }

    // --- keys: 64 (seq,step) pairs, 16 lanes x 8 elems each ---
    {
        int pair = tid >> 4;        // 0..63
        int seq = pair >> 4, st = pair & 15;
        int ln = tid & 15;
        const float* e = emb + (seq * N_STEPS + st) * 128 + ln * 8;
        const float* pr = proj + ln * 8;
        float kk = 0.0f;
        #pragma unroll
        for (int d = 0; d < 8; d++) kk = fmaf(e[d], pr[d], kk);
        sh[tid] = kk;
        __syncthreads();
        for (int off = 8; off > 0; off >>= 1) {
            if (ln < off) sh[tid] += sh[tid + off];
            __syncthreads();
        }
        if (ln == 0) keys[seq][st] = sh[tid];
        __syncthreads();
    }

    // --- stable ascending argsort, 4 threads ---
    if (tid < NSEQ) {
        int ord[N_STEPS];
        for (int i = 0; i < N_STEPS; i++) ord[i] = i;
        for (int i = 1; i < N_STEPS; i++) {
            int oi = ord[i];
            float kv = keys[tid][oi];
            int j = i - 1;
            while (j >= 0 && keys[tid][ord[j]] > kv) { ord[j + 1] = ord[j]; j--; }
            ord[j + 1] = oi;
        }
        for (int i = 0; i < N_STEPS; i++) order[tid][i] = ord[i];
    }
    __syncthreads();

    // --- MSE over 2*16*128 = 4096 elems (pow2 index math) ---
    float s = 0.0f;
    #pragma unroll
    for (int t = 0; t < 4; t++) {
        int idx = tid + t * 1024;
        int b  = idx >> 11;
        int st = (idx >> 7) & 15;
        int d  = idx & 127;
        float va = emb[((b    ) * N_STEPS + order[b    ][st]) * 128 + d];
        float vb = emb[((2 + b) * N_STEPS + order[2 + b][st]) * 128 + d];
        float df = va - vb;
        s = fmaf(df, df, s);
    }
    sh[tid] = s;
    __syncthreads();
    for (int off = 512; off > 0; off >>= 1) {
        if (tid < off) sh[tid] += sh[tid + off];
        __syncthreads();
    }
    if (tid == 0) {
        float mse = sh[0] / 4096.0f;
        float mad = 0.5f * (fabsf(norms[0] - norms[2]) + fabsf(norms[1] - norms[3]));
        out[0] = mse + mad;
    }
}

// ---------------------------------------------------------------------------
extern "C" void kernel_launch(void* const* d_in, const int* in_sizes, int n_in,
                              void* d_out, int out_size, void* d_ws, size_t ws_size,
                              hipStream_t stream) {
    const float* a    = (const float*)d_in[0];
    const float* b    = (const float*)d_in[1];
    const float* d    = (const float*)d_in[2];
    const float* ae   = (const float*)d_in[3];
    const float* proj = (const float*)d_in[4];
    float* out = (float*)d_out;

    float* ws  = (float*)d_ws;
    float* res = ws;                              // 65536 f
    float* du  = res + NSEQ * T_DIM;              // 16384 f
    float* emb = du + A_DIM * K_DIM;              // 8192 f
    unsigned long long* pmax = (unsigned long long*)(emb + NSEQ * N_STEPS * 128); // 8B-aligned
    int* cnt   = (int*)(pmax + NSEQ * NB_PER_SEQ);
    int* dirty = cnt + N_STEPS * NSEQ;

    k_dunit<<<A_DIM, K_DIM, 0, stream>>>(d, du);
    k_init<<<NSEQ * T_DIM / 256, 256, 0, stream>>>(a, b, res, cnt, dirty);

    dim3 gfull(NB_PER_SEQ, NSEQ);
    k_step_full<<<gfull, 256, 0, stream>>>(res, du, ae, emb, pmax, cnt, dirty);

    dim3 ginc(8, NSEQ);
    for (int step = 1; step < N_STEPS; step++) {
        k_step_inc<<<ginc, 256, 0, stream>>>(res, du, ae, emb, pmax, cnt, dirty, step);
    }

    k_tail<<<1, 1024, 0, stream>>>(res, emb, proj, out);
}